// Round 2
// baseline (195.123 us; speedup 1.0000x reference)
//
#include <hip/hip_runtime.h>

// S4 -> causal conv. y[b,t] = d*u0[b,t] + sum_j k[j]*u0[b,t-j], k[j]=c^T Abar^j bbar.
// Abar = expm(dt*A): scale (theta=2) + Taylor-15 Paterson-Stockmeyer + squarings.
// bbar = dt*phi1(dtA)B: phi1 by PS on vectors + doubling through the squarings.
// k = CQ^T BR bilinear split; BR/CQ stored TRANSPOSED (BRT/CQT) so every matmul
// reads operands as rows (coalesced) or from LDS. Hot chain (all squarings) lives
// in ONE LDS slot S0, in-place: stage S0->FRAG(bf16 hi/lo), MFMA, write back.
//
// 256 threads (4 waves == 4 MFMA warps, no idle waves). Every op is
// sync-SANDWICHED (entry + end barriers; mm: entry+mid+end) -- strictly more
// synchronization than the verified 1024-thread baseline, so no op-boundary
// ordering can race. mv uses 4-lane shfl-group reduction (1 row per 4 lanes).
//
// ws floats: [0,4096) k | [4096,20480) u0 | 20480 gX | 24832 gX2 | 29184 gX3
//            | 33536 gU0 | 37888 gU1 | 42240 gBRT | 46592 gCQT   (203776 B)

#define NT 256
#define MP 68
#define MB (64 * MP)

typedef __attribute__((ext_vector_type(8))) short v8s;
typedef __attribute__((ext_vector_type(4))) float v4f;

__device__ __forceinline__ unsigned short bf16r(float x) {
  union { float f; unsigned u; } v; v.f = x;
  unsigned r = v.u + 0x7fffu + ((v.u >> 16) & 1u);
  return (unsigned short)(r >> 16);
}
__device__ __forceinline__ float bf2f(unsigned short h) {
  union { unsigned u; float f; } v; v.u = ((unsigned)h) << 16;
  return v.f;
}
__device__ __forceinline__ void cvt4(const float4 f, ushort4* H, ushort4* L) {
  unsigned short h;
  h = bf16r(f.x); H->x = h; L->x = bf16r(f.x - bf2f(h));
  h = bf16r(f.y); H->y = h; L->y = bf16r(f.y - bf2f(h));
  h = bf16r(f.z); H->z = h; L->z = bf16r(f.z - bf2f(h));
  h = bf16r(f.w); H->w = h; L->w = bf16r(f.w - bf2f(h));
}

// FRAG layout (ushorts): A-hi @0, A-lo @4096, B-hi @8192, B-lo @12288.
// C[rowbase+i][colbase+j] = sum_k A[i][k]*B[k][j], pitches MP (Cd: cpitch).
// A rows at Ag (LDS or global). B: bT=0 -> B[k][n]=Bs[k*MP+n] (column staging);
// bT=1 -> B[k][n]=Bs[n*MP+k] (row staging of B^T). Tiles: R<nrt, Cc<nct.
// In-place safe for Cd==Ag==Bs (all staging reads complete before epilogue).
__device__ void mm(const float* Ag, const float* Bs, int bT,
                   float* Cd, int cpitch, float* Cd2,
                   int nrt, int nct, int rowbase, int colbase,
                   unsigned short* FRAG) {
  const int t = threadIdx.x;
  __syncthreads();  // entry: inputs visible regardless of caller state
  for (int s0 = 0; s0 < 512; s0 += 256) {
    const int s = s0 + t;
    const int l = s & 63, Tq = s >> 6;
    const int mrow = (Tq >> 1) * 16 + (l & 15);
    const int kk = (Tq & 1) * 32 + (l >> 4) * 8;
    const float* ap = Ag + mrow * MP + kk;
    const float4 f0 = *(const float4*)ap;
    const float4 f1 = *(const float4*)(ap + 4);
    ushort4 H0, L0, H1, L1;
    cvt4(f0, &H0, &L0); cvt4(f1, &H1, &L1);
    *(ushort4*)(FRAG + s * 8)            = H0;
    *(ushort4*)(FRAG + s * 8 + 4)        = H1;
    *(ushort4*)(FRAG + 4096 + s * 8)     = L0;
    *(ushort4*)(FRAG + 4096 + s * 8 + 4) = L1;
    float4 g0, g1;
    if (bT) {
      const float* bp = Bs + mrow * MP + kk;
      g0 = *(const float4*)bp;
      g1 = *(const float4*)(bp + 4);
    } else {
      g0.x = Bs[(kk + 0) * MP + mrow]; g0.y = Bs[(kk + 1) * MP + mrow];
      g0.z = Bs[(kk + 2) * MP + mrow]; g0.w = Bs[(kk + 3) * MP + mrow];
      g1.x = Bs[(kk + 4) * MP + mrow]; g1.y = Bs[(kk + 5) * MP + mrow];
      g1.z = Bs[(kk + 6) * MP + mrow]; g1.w = Bs[(kk + 7) * MP + mrow];
    }
    cvt4(g0, &H0, &L0); cvt4(g1, &H1, &L1);
    *(ushort4*)(FRAG + 8192 + s * 8)      = H0;
    *(ushort4*)(FRAG + 8192 + s * 8 + 4)  = H1;
    *(ushort4*)(FRAG + 12288 + s * 8)     = L0;
    *(ushort4*)(FRAG + 12288 + s * 8 + 4) = L1;
  }
  __syncthreads();  // mid: staging complete before epilogue reads/writes
  {
    const int w = t >> 6, l = t & 63;
    if (w < nrt) {
      const v8s Ah0 = *(const v8s*)(FRAG + ((w * 2 + 0) * 64 + l) * 8);
      const v8s Ah1 = *(const v8s*)(FRAG + ((w * 2 + 1) * 64 + l) * 8);
      const v8s Al0 = *(const v8s*)(FRAG + 4096 + ((w * 2 + 0) * 64 + l) * 8);
      const v8s Al1 = *(const v8s*)(FRAG + 4096 + ((w * 2 + 1) * 64 + l) * 8);
      for (int Cc = 0; Cc < nct; ++Cc) {
        const v8s Bh0 = *(const v8s*)(FRAG + 8192 + ((Cc * 2 + 0) * 64 + l) * 8);
        const v8s Bh1 = *(const v8s*)(FRAG + 8192 + ((Cc * 2 + 1) * 64 + l) * 8);
        const v8s Bl0 = *(const v8s*)(FRAG + 12288 + ((Cc * 2 + 0) * 64 + l) * 8);
        const v8s Bl1 = *(const v8s*)(FRAG + 12288 + ((Cc * 2 + 1) * 64 + l) * 8);
        const v4f z = {0.f, 0.f, 0.f, 0.f};
        v4f a0 = __builtin_amdgcn_mfma_f32_16x16x32_bf16(Ah0, Bh0, z, 0, 0, 0);
        a0 = __builtin_amdgcn_mfma_f32_16x16x32_bf16(Ah1, Bh1, a0, 0, 0, 0);
        v4f a1 = __builtin_amdgcn_mfma_f32_16x16x32_bf16(Ah0, Bl0, z, 0, 0, 0);
        a1 = __builtin_amdgcn_mfma_f32_16x16x32_bf16(Ah1, Bl1, a1, 0, 0, 0);
        v4f a2 = __builtin_amdgcn_mfma_f32_16x16x32_bf16(Al0, Bh0, z, 0, 0, 0);
        a2 = __builtin_amdgcn_mfma_f32_16x16x32_bf16(Al1, Bh1, a2, 0, 0, 0);
        const int col = colbase + Cc * 16 + (l & 15);
        const int r0 = rowbase + w * 16 + (l >> 4) * 4;
        const float o0 = a0[0] + a1[0] + a2[0];
        const float o1 = a0[1] + a1[1] + a2[1];
        const float o2 = a0[2] + a1[2] + a2[2];
        const float o3 = a0[3] + a1[3] + a2[3];
        Cd[(r0 + 0) * cpitch + col] = o0;
        Cd[(r0 + 1) * cpitch + col] = o1;
        Cd[(r0 + 2) * cpitch + col] = o2;
        Cd[(r0 + 3) * cpitch + col] = o3;
        if (Cd2) {
          Cd2[(r0 + 0) * MP + col] = o0;
          Cd2[(r0 + 1) * MP + col] = o1;
          Cd2[(r0 + 2) * MP + col] = o2;
          Cd2[(r0 + 3) * MP + col] = o3;
        }
      }
    }
  }
  __syncthreads();  // end: outputs visible
}

// vout = M*vin (rows of M, pitch MP). 4 lanes per row, shfl-xor reduce.
// half: vout = 0.5*(M*vin + vin) (phi1 doubling; vout must != vin).
// out2: also store result there (BRT row capture). Entry+end barriers.
__device__ __forceinline__ void mv64row(const float* M, const float* vin,
                                        float* vout, float* out2, int half) {
  const int t = threadIdx.x;
  __syncthreads();
  const int w = t >> 6, l = t & 63;
  const int row = w * 16 + (l >> 2), q = l & 3;
  const float* mp = M + row * MP + q * 16;
  const float* vp = vin + q * 16;
  float p = 0.f;
#pragma unroll
  for (int j = 0; j < 16; j += 4) {
    const float4 m = *(const float4*)(mp + j);
    p = fmaf(m.x, vp[j + 0], p);
    p = fmaf(m.y, vp[j + 1], p);
    p = fmaf(m.z, vp[j + 2], p);
    p = fmaf(m.w, vp[j + 3], p);
  }
  p += __shfl_xor(p, 1);
  p += __shfl_xor(p, 2);
  if (q == 0) {
    float s = half ? 0.5f * (p + vin[row]) : p;
    vout[row] = s;
    if (out2) out2[row] = s;
  }
  __syncthreads();
}

// vout = M^T*vin. 4 lanes per output col, shfl-xor reduce. Entry+end barriers.
__device__ __forceinline__ void mv64colT(const float* M, const float* vin,
                                         float* vout, float* out2) {
  const int t = threadIdx.x;
  __syncthreads();
  const int w = t >> 6, l = t & 63;
  const int col = w * 16 + (l >> 2), q = l & 3;
  float p = 0.f;
#pragma unroll
  for (int j = 0; j < 16; ++j)
    p = fmaf(M[(q * 16 + j) * MP + col], vin[q * 16 + j], p);
  p += __shfl_xor(p, 1);
  p += __shfl_xor(p, 2);
  if (q == 0) {
    vout[col] = p;
    if (out2) out2[col] = p;
  }
  __syncthreads();
}

// dst = c0*I + c1*X + c2*X2 + c3*X3 (+ addsrc). Element-wise, pitch MP.
// Entry+end barriers. Diagonal add via per-element compares (no runtime
// indexing into the float4 -- avoids scratch allocation).
__device__ void buildG(float* dst, const float* X, const float* X2, const float* X3,
                       float c0, float c1, float c2, float c3, const float* addsrc) {
  const int t = threadIdx.x;
  __syncthreads();
  const int r = t >> 2, cb = (t & 3) * 16;
#pragma unroll
  for (int j = 0; j < 16; j += 4) {
    const int c = cb + j;
    const int e = r * MP + c;
    const float4 x1 = *(const float4*)(X + e);
    const float4 x2 = *(const float4*)(X2 + e);
    const float4 x3 = *(const float4*)(X3 + e);
    float4 v;
    v.x = fmaf(c1, x1.x, fmaf(c2, x2.x, c3 * x3.x));
    v.y = fmaf(c1, x1.y, fmaf(c2, x2.y, c3 * x3.y));
    v.z = fmaf(c1, x1.z, fmaf(c2, x2.z, c3 * x3.z));
    v.w = fmaf(c1, x1.w, fmaf(c2, x2.w, c3 * x3.w));
    if (r == c + 0) v.x += c0;
    if (r == c + 1) v.y += c0;
    if (r == c + 2) v.z += c0;
    if (r == c + 3) v.w += c0;
    if (addsrc) {
      const float4 a = *(const float4*)(addsrc + e);
      v.x += a.x; v.y += a.y; v.z += a.z; v.w += a.w;
    }
    *(float4*)(dst + e) = v;
  }
  __syncthreads();
}

__global__ __launch_bounds__(NT) void s4_setup(const float* __restrict__ u,
    const float* __restrict__ A, const float* __restrict__ Bv,
    const float* __restrict__ Cv, const float* __restrict__ logdt,
    float* __restrict__ ws) {
  if (blockIdx.x > 0) {
    const int idx = (blockIdx.x - 1) * NT + threadIdx.x;  // 0..16383
    ws[4096 + idx] = u[(size_t)idx * 1024];
    return;
  }
  __shared__ __align__(16) float S0[MB];
  __shared__ __align__(16) unsigned short FRAG[16384];
  __shared__ float vB[64], v1[64], v2[64], v3[64], va[64], vb[64], vg[64];
  __shared__ int s_s;
  float* vscr = (float*)FRAG;  // overlay: only used by the 1-norm (pre-mm)

  const int t = threadIdx.x;
  float* kbuf = ws;
  float* gX   = ws + 20480;
  float* gX2  = ws + 24832;
  float* gX3  = ws + 29184;
  float* gU0  = ws + 33536;
  float* gU1  = ws + 37888;
  float* gBRT = ws + 42240;
  float* gCQT = ws + 46592;
  const float dt = expf(logdt[0]);

  const float invf[17] = {1.f, 1.f, 1.f / 2.f, 1.f / 6.f, 1.f / 24.f, 1.f / 120.f,
                          1.f / 720.f, 1.f / 5040.f, 1.f / 40320.f, 1.f / 362880.f,
                          1.f / 3628800.f, 1.f / 39916800.f, 1.f / 479001600.f,
                          1.f / 6.2270208e9f, 1.f / 8.71782912e10f,
                          1.f / 1.307674368e12f, 1.f / 2.0922789888e13f};

  // ---- 1-norm of dt*A -> s (theta = 2) ----
  {
    const int j = t & 63, w = t >> 6;
    float p = 0.f;
#pragma unroll
    for (int ii = 0; ii < 16; ++ii) p += fabsf(A[(w * 16 + ii) * 64 + j]);
    vscr[t] = p;
    __syncthreads();
    if (t < 64) {
      float cs = vscr[t] + vscr[64 + t] + vscr[128 + t] + vscr[192 + t];
      cs *= dt;
#pragma unroll
      for (int off = 32; off > 0; off >>= 1) cs = fmaxf(cs, __shfl_xor(cs, off));
      if (t == 0) {
        int s = 0;
        while (cs > 2.0f && s < 30) { cs *= 0.5f; ++s; }
        s_s = s;
      }
    }
    __syncthreads();
  }
  const int sq = s_s;
  const float scl = ldexpf(dt, -sq);

  // ---- X -> S0 and gX; vB ----
  {
    const int r = t >> 2, cb = (t & 3) * 16;
#pragma unroll
    for (int j = 0; j < 16; j += 4) {
      const float4 a4 = *(const float4*)(A + r * 64 + cb + j);
      float4 x;
      x.x = a4.x * scl; x.y = a4.y * scl; x.z = a4.z * scl; x.w = a4.w * scl;
      *(float4*)(S0 + r * MP + cb + j) = x;
      *(float4*)(gX + r * MP + cb + j) = x;
    }
    if (t < 64) vB[t] = Bv[t];
    __syncthreads();
  }

  // ---- powers: X2 (S0, +gX2), X3 (gX3), X4 (S0 in-place) ----
  mm(S0, S0, 0, S0, MP, gX2, 4, 4, 0, 0, FRAG);        // X2
  mm(gX, S0, 0, gX3, MP, nullptr, 4, 4, 0, 0, FRAG);   // X3 = X*X2
  mm(S0, S0, 0, S0, MP, nullptr, 4, 4, 0, 0, FRAG);    // X4 = X2*X2

  // ---- phi1(X)*B via PS on vectors (deg-15, groups of 4 in X4) ----
  mv64row(gX,  vB, v1, nullptr, 0);
  mv64row(gX2, vB, v2, nullptr, 0);
  mv64row(gX3, vB, v3, nullptr, 0);
  if (t < 64)
    va[t] = invf[13] * vB[t] + invf[14] * v1[t] + invf[15] * v2[t] + invf[16] * v3[t];
  __syncthreads();
  mv64row(S0, va, vb, nullptr, 0);
  if (t < 64)
    va[t] = invf[9] * vB[t] + invf[10] * v1[t] + invf[11] * v2[t] + invf[12] * v3[t] + vb[t];
  __syncthreads();
  mv64row(S0, va, vb, nullptr, 0);
  if (t < 64)
    va[t] = invf[5] * vB[t] + invf[6] * v1[t] + invf[7] * v2[t] + invf[8] * v3[t] + vb[t];
  __syncthreads();
  mv64row(S0, va, vb, nullptr, 0);
  if (t < 64)
    vg[t] = invf[1] * vB[t] + invf[2] * v1[t] + invf[3] * v2[t] + invf[4] * v3[t] + vb[t];
  __syncthreads();

  // ---- e^X: Taylor-15 PS Horner (B-operand X4 in S0) ----
  buildG(gU0, gX, gX2, gX3, invf[12], invf[13], invf[14], invf[15], nullptr);
  mm(gU0, S0, 0, gU1, MP, nullptr, 4, 4, 0, 0, FRAG);
  buildG(gU1, gX, gX2, gX3, invf[8], invf[9], invf[10], invf[11], gU1);
  mm(gU1, S0, 0, gU0, MP, nullptr, 4, 4, 0, 0, FRAG);
  buildG(gU0, gX, gX2, gX3, invf[4], invf[5], invf[6], invf[7], gU0);
  mm(gU0, S0, 0, S0, MP, nullptr, 4, 4, 0, 0, FRAG);   // -> S0 (over X4)
  buildG(S0, gX, gX2, gX3, invf[0], invf[1], invf[2], invf[3], S0);  // S0 = e^X

  // ---- squarings + phi1 doubling: g <- (F+I)g/2 (ping-pong vg/va) ----
  float* vcur = vg;
  float* vnxt = va;
  for (int it = 0; it < sq; ++it) {
    mv64row(S0, vcur, vnxt, nullptr, 1);  // vnxt = 0.5*(S0*vcur + vcur)
    { float* tmp = vcur; vcur = vnxt; vnxt = tmp; }
    mm(S0, S0, 0, S0, MP, nullptr, 4, 4, 0, 0, FRAG);
  }
  // S0 = Abar, vcur = phi1 vector

  // ---- BRT rows 0..15: bbar then Abar^r bbar (row store folded into mv) ----
  if (t < 64) {
    const float bb = dt * vcur[t];
    v1[t] = bb;
    gBRT[t] = bb;
  }
  __syncthreads();
  {
    float* vc = v1; float* vn = v2;
    for (int r = 1; r < 16; ++r) {
      mv64row(S0, vc, vn, gBRT + r * MP, 0);
      float* tmp = vc; vc = vn; vn = tmp;
    }
  }

  // ---- P-chain (in-place) + BRT widenings ----
  mm(S0, S0, 0, S0, MP, nullptr, 4, 4, 0, 0, FRAG);        // P2
  mm(S0, S0, 0, S0, MP, nullptr, 4, 4, 0, 0, FRAG);        // P4
  mm(S0, S0, 0, S0, MP, nullptr, 4, 4, 0, 0, FRAG);        // P8
  mm(S0, S0, 0, S0, MP, nullptr, 4, 4, 0, 0, FRAG);        // P16
  mm(gBRT, S0, 1, gBRT, MP, nullptr, 1, 4, 16, 0, FRAG);   // rows16:32 = BRT0:16*P16^T
  mm(S0, S0, 0, S0, MP, nullptr, 4, 4, 0, 0, FRAG);        // P32
  mm(gBRT, S0, 1, gBRT, MP, nullptr, 2, 4, 32, 0, FRAG);   // rows32:64
  mm(S0, S0, 0, S0, MP, nullptr, 4, 4, 0, 0, FRAG);        // P64

  // ---- CQT rows 0..15: c then (P64^T)^q c (row store folded into mv) ----
  if (t < 64) {
    const float cc = Cv[t];
    v1[t] = cc;
    gCQT[t] = cc;
  }
  __syncthreads();
  {
    float* vc = v1; float* vn = v2;
    for (int qx = 1; qx < 16; ++qx) {
      mv64colT(S0, vc, vn, gCQT + qx * MP);
      float* tmp = vc; vc = vn; vn = tmp;
    }
  }

  // ---- A-chain (in-place) + CQT widenings ----
  mm(S0, S0, 0, S0, MP, nullptr, 4, 4, 0, 0, FRAG);        // A128
  mm(S0, S0, 0, S0, MP, nullptr, 4, 4, 0, 0, FRAG);        // A256
  mm(S0, S0, 0, S0, MP, nullptr, 4, 4, 0, 0, FRAG);        // A512
  mm(S0, S0, 0, S0, MP, nullptr, 4, 4, 0, 0, FRAG);        // A1024
  mm(gCQT, S0, 0, gCQT, MP, nullptr, 1, 4, 16, 0, FRAG);   // rows16:32 = CQT0:16*A1024
  mm(S0, S0, 0, S0, MP, nullptr, 4, 4, 0, 0, FRAG);        // A2048
  mm(gCQT, S0, 0, gCQT, MP, nullptr, 2, 4, 32, 0, FRAG);   // rows32:64

  // ---- k[q*64+r] = sum_i CQT[q][i]*BRT[r][i] ----
  mm(gCQT, gBRT, 1, kbuf, 64, nullptr, 4, 4, 0, 0, FRAG);
}

// Fused conv + broadcast: 4096 blocks x 256 threads; block computes 4 y-scalars
// then streams 4 rows x 1024 cols of broadcast float4 stores (write-bound).
__global__ __launch_bounds__(256) void s4_out(const float* __restrict__ ws,
                                              const float* __restrict__ Dp,
                                              float* __restrict__ out) {
  const int bid = blockIdx.x;
  const int b = bid >> 10;
  const int t0 = (bid & 1023) << 2;
  const float* kb = ws;
  const float* ub = ws + 4096 + (b << 12);
  const int tid = threadIdx.x;
  const int t3 = t0 + 3;
  float a0 = 0.f, a1 = 0.f, a2 = 0.f, a3 = 0.f;
  for (int j = tid; j <= t3; j += 256) {
    const float kj = kb[j];
    if (j <= t0)     a0 = fmaf(kj, ub[t0 - j], a0);
    if (j <= t0 + 1) a1 = fmaf(kj, ub[t0 + 1 - j], a1);
    if (j <= t0 + 2) a2 = fmaf(kj, ub[t0 + 2 - j], a2);
    a3 = fmaf(kj, ub[t3 - j], a3);
  }
#pragma unroll
  for (int off = 32; off > 0; off >>= 1) {
    a0 += __shfl_xor(a0, off);
    a1 += __shfl_xor(a1, off);
    a2 += __shfl_xor(a2, off);
    a3 += __shfl_xor(a3, off);
  }
  __shared__ float red[4][4];
  __shared__ float sy[4];
  if ((tid & 63) == 0) {
    const int w = tid >> 6;
    red[0][w] = a0; red[1][w] = a1; red[2][w] = a2; red[3][w] = a3;
  }
  __syncthreads();
  if (tid < 4)
    sy[tid] = red[tid][0] + red[tid][1] + red[tid][2] + red[tid][3] +
              Dp[0] * ub[t0 + tid];
  __syncthreads();
  const int row = tid >> 6, l = tid & 63;
  const float y = sy[row];
  const float4 y4 = make_float4(y, y, y, y);
  float4* dst = (float4*)(out + ((size_t)(b << 12) + t0 + row) * 1024);
  dst[l] = y4; dst[l + 64] = y4; dst[l + 128] = y4; dst[l + 192] = y4;
}

extern "C" void kernel_launch(void* const* d_in, const int* in_sizes, int n_in,
                              void* d_out, int out_size, void* d_ws, size_t ws_size,
                              hipStream_t stream) {
  const float* u  = (const float*)d_in[0];
  const float* A  = (const float*)d_in[1];
  const float* B  = (const float*)d_in[2];
  const float* C  = (const float*)d_in[3];
  const float* D  = (const float*)d_in[4];
  const float* ld = (const float*)d_in[5];
  float* ws = (float*)d_ws;  // needs >= 203776 bytes

  s4_setup<<<65, NT, 0, stream>>>(u, A, B, C, ld, ws);
  s4_out<<<4096, 256, 0, stream>>>(ws, D, (float*)d_out);
}

// Round 4
// 187.372 us; speedup vs baseline: 1.0414x; 1.0414x over previous
//
#include <hip/hip_runtime.h>

// S4 -> causal conv. y[b,t] = d*u0[b,t] + sum_j k[j]*u0[b,t-j], k[j]=c^T Abar^j bbar.
// Abar = expm(dt*A): scale (theta=2) + Taylor-15 Paterson-Stockmeyer + squarings.
// bbar = dt*phi1(dtA)B: phi1 by PS on vectors + doubling through the squarings.
// k = CQ^T BR bilinear split; BR/CQ stored TRANSPOSED (BRT/CQT) so every matmul
// reads operands as rows (coalesced) or from LDS. Hot chain (all squarings) lives
// in ONE LDS slot S0, in-place: stage S0->FRAG(bf16 hi/lo), MFMA, write back.
//
// setup: 256 threads (4 waves == 4 MFMA warps), sync-sandwiched ops (verified r2).
// out:   conv rewritten as aligned sliding-window float4 (3 loads / 16 FMA);
//        r0's scalar version issued ~42M VMEM loads (issue-bound ~66us);
//        this issues ~6M. Broadcast stores nontemporal via v4f (clang ext-vector;
//        HIP float4 is a class type the builtin rejects).
//
// ws floats: [0,4096) k | [4096,20480) u0 | 20480 gX | 24832 gX2 | 29184 gX3
//            | 33536 gU0 | 37888 gU1 | 42240 gBRT | 46592 gCQT   (203776 B)

#define NT 256
#define MP 68
#define MB (64 * MP)

typedef __attribute__((ext_vector_type(8))) short v8s;
typedef __attribute__((ext_vector_type(4))) float v4f;

__device__ __forceinline__ unsigned short bf16r(float x) {
  union { float f; unsigned u; } v; v.f = x;
  unsigned r = v.u + 0x7fffu + ((v.u >> 16) & 1u);
  return (unsigned short)(r >> 16);
}
__device__ __forceinline__ float bf2f(unsigned short h) {
  union { unsigned u; float f; } v; v.u = ((unsigned)h) << 16;
  return v.f;
}
__device__ __forceinline__ void cvt4(const float4 f, ushort4* H, ushort4* L) {
  unsigned short h;
  h = bf16r(f.x); H->x = h; L->x = bf16r(f.x - bf2f(h));
  h = bf16r(f.y); H->y = h; L->y = bf16r(f.y - bf2f(h));
  h = bf16r(f.z); H->z = h; L->z = bf16r(f.z - bf2f(h));
  h = bf16r(f.w); H->w = h; L->w = bf16r(f.w - bf2f(h));
}

// FRAG layout (ushorts): A-hi @0, A-lo @4096, B-hi @8192, B-lo @12288.
// C[rowbase+i][colbase+j] = sum_k A[i][k]*B[k][j], pitches MP (Cd: cpitch).
// A rows at Ag (LDS or global). B: bT=0 -> B[k][n]=Bs[k*MP+n] (column staging);
// bT=1 -> B[k][n]=Bs[n*MP+k] (row staging of B^T). Tiles: R<nrt, Cc<nct.
// In-place safe for Cd==Ag==Bs (all staging reads complete before epilogue).
__device__ void mm(const float* Ag, const float* Bs, int bT,
                   float* Cd, int cpitch, float* Cd2,
                   int nrt, int nct, int rowbase, int colbase,
                   unsigned short* FRAG) {
  const int t = threadIdx.x;
  __syncthreads();  // entry: inputs visible regardless of caller state
  for (int s0 = 0; s0 < 512; s0 += 256) {
    const int s = s0 + t;
    const int l = s & 63, Tq = s >> 6;
    const int mrow = (Tq >> 1) * 16 + (l & 15);
    const int kk = (Tq & 1) * 32 + (l >> 4) * 8;
    const float* ap = Ag + mrow * MP + kk;
    const float4 f0 = *(const float4*)ap;
    const float4 f1 = *(const float4*)(ap + 4);
    ushort4 H0, L0, H1, L1;
    cvt4(f0, &H0, &L0); cvt4(f1, &H1, &L1);
    *(ushort4*)(FRAG + s * 8)            = H0;
    *(ushort4*)(FRAG + s * 8 + 4)        = H1;
    *(ushort4*)(FRAG + 4096 + s * 8)     = L0;
    *(ushort4*)(FRAG + 4096 + s * 8 + 4) = L1;
    float4 g0, g1;
    if (bT) {
      const float* bp = Bs + mrow * MP + kk;
      g0 = *(const float4*)bp;
      g1 = *(const float4*)(bp + 4);
    } else {
      g0.x = Bs[(kk + 0) * MP + mrow]; g0.y = Bs[(kk + 1) * MP + mrow];
      g0.z = Bs[(kk + 2) * MP + mrow]; g0.w = Bs[(kk + 3) * MP + mrow];
      g1.x = Bs[(kk + 4) * MP + mrow]; g1.y = Bs[(kk + 5) * MP + mrow];
      g1.z = Bs[(kk + 6) * MP + mrow]; g1.w = Bs[(kk + 7) * MP + mrow];
    }
    cvt4(g0, &H0, &L0); cvt4(g1, &H1, &L1);
    *(ushort4*)(FRAG + 8192 + s * 8)      = H0;
    *(ushort4*)(FRAG + 8192 + s * 8 + 4)  = H1;
    *(ushort4*)(FRAG + 12288 + s * 8)     = L0;
    *(ushort4*)(FRAG + 12288 + s * 8 + 4) = L1;
  }
  __syncthreads();  // mid: staging complete before epilogue reads/writes
  {
    const int w = t >> 6, l = t & 63;
    if (w < nrt) {
      const v8s Ah0 = *(const v8s*)(FRAG + ((w * 2 + 0) * 64 + l) * 8);
      const v8s Ah1 = *(const v8s*)(FRAG + ((w * 2 + 1) * 64 + l) * 8);
      const v8s Al0 = *(const v8s*)(FRAG + 4096 + ((w * 2 + 0) * 64 + l) * 8);
      const v8s Al1 = *(const v8s*)(FRAG + 4096 + ((w * 2 + 1) * 64 + l) * 8);
      for (int Cc = 0; Cc < nct; ++Cc) {
        const v8s Bh0 = *(const v8s*)(FRAG + 8192 + ((Cc * 2 + 0) * 64 + l) * 8);
        const v8s Bh1 = *(const v8s*)(FRAG + 8192 + ((Cc * 2 + 1) * 64 + l) * 8);
        const v8s Bl0 = *(const v8s*)(FRAG + 12288 + ((Cc * 2 + 0) * 64 + l) * 8);
        const v8s Bl1 = *(const v8s*)(FRAG + 12288 + ((Cc * 2 + 1) * 64 + l) * 8);
        const v4f z = {0.f, 0.f, 0.f, 0.f};
        v4f a0 = __builtin_amdgcn_mfma_f32_16x16x32_bf16(Ah0, Bh0, z, 0, 0, 0);
        a0 = __builtin_amdgcn_mfma_f32_16x16x32_bf16(Ah1, Bh1, a0, 0, 0, 0);
        v4f a1 = __builtin_amdgcn_mfma_f32_16x16x32_bf16(Ah0, Bl0, z, 0, 0, 0);
        a1 = __builtin_amdgcn_mfma_f32_16x16x32_bf16(Ah1, Bl1, a1, 0, 0, 0);
        v4f a2 = __builtin_amdgcn_mfma_f32_16x16x32_bf16(Al0, Bh0, z, 0, 0, 0);
        a2 = __builtin_amdgcn_mfma_f32_16x16x32_bf16(Al1, Bh1, a2, 0, 0, 0);
        const int col = colbase + Cc * 16 + (l & 15);
        const int r0 = rowbase + w * 16 + (l >> 4) * 4;
        const float o0 = a0[0] + a1[0] + a2[0];
        const float o1 = a0[1] + a1[1] + a2[1];
        const float o2 = a0[2] + a1[2] + a2[2];
        const float o3 = a0[3] + a1[3] + a2[3];
        Cd[(r0 + 0) * cpitch + col] = o0;
        Cd[(r0 + 1) * cpitch + col] = o1;
        Cd[(r0 + 2) * cpitch + col] = o2;
        Cd[(r0 + 3) * cpitch + col] = o3;
        if (Cd2) {
          Cd2[(r0 + 0) * MP + col] = o0;
          Cd2[(r0 + 1) * MP + col] = o1;
          Cd2[(r0 + 2) * MP + col] = o2;
          Cd2[(r0 + 3) * MP + col] = o3;
        }
      }
    }
  }
  __syncthreads();  // end: outputs visible
}

// vout = M*vin (rows of M, pitch MP). 4 lanes per row, shfl-xor reduce.
// half: vout = 0.5*(M*vin + vin) (phi1 doubling; vout must != vin).
// out2: also store result there (BRT row capture). Entry+end barriers.
__device__ __forceinline__ void mv64row(const float* M, const float* vin,
                                        float* vout, float* out2, int half) {
  const int t = threadIdx.x;
  __syncthreads();
  const int w = t >> 6, l = t & 63;
  const int row = w * 16 + (l >> 2), q = l & 3;
  const float* mp = M + row * MP + q * 16;
  const float* vp = vin + q * 16;
  float p = 0.f;
#pragma unroll
  for (int j = 0; j < 16; j += 4) {
    const float4 m = *(const float4*)(mp + j);
    p = fmaf(m.x, vp[j + 0], p);
    p = fmaf(m.y, vp[j + 1], p);
    p = fmaf(m.z, vp[j + 2], p);
    p = fmaf(m.w, vp[j + 3], p);
  }
  p += __shfl_xor(p, 1);
  p += __shfl_xor(p, 2);
  if (q == 0) {
    float s = half ? 0.5f * (p + vin[row]) : p;
    vout[row] = s;
    if (out2) out2[row] = s;
  }
  __syncthreads();
}

// vout = M^T*vin. 4 lanes per output col, shfl-xor reduce. Entry+end barriers.
__device__ __forceinline__ void mv64colT(const float* M, const float* vin,
                                         float* vout, float* out2) {
  const int t = threadIdx.x;
  __syncthreads();
  const int w = t >> 6, l = t & 63;
  const int col = w * 16 + (l >> 2), q = l & 3;
  float p = 0.f;
#pragma unroll
  for (int j = 0; j < 16; ++j)
    p = fmaf(M[(q * 16 + j) * MP + col], vin[q * 16 + j], p);
  p += __shfl_xor(p, 1);
  p += __shfl_xor(p, 2);
  if (q == 0) {
    vout[col] = p;
    if (out2) out2[col] = p;
  }
  __syncthreads();
}

// dst = c0*I + c1*X + c2*X2 + c3*X3 (+ addsrc). Element-wise, pitch MP.
// Entry+end barriers. Diagonal add via per-element compares.
__device__ void buildG(float* dst, const float* X, const float* X2, const float* X3,
                       float c0, float c1, float c2, float c3, const float* addsrc) {
  const int t = threadIdx.x;
  __syncthreads();
  const int r = t >> 2, cb = (t & 3) * 16;
#pragma unroll
  for (int j = 0; j < 16; j += 4) {
    const int c = cb + j;
    const int e = r * MP + c;
    const float4 x1 = *(const float4*)(X + e);
    const float4 x2 = *(const float4*)(X2 + e);
    const float4 x3 = *(const float4*)(X3 + e);
    float4 v;
    v.x = fmaf(c1, x1.x, fmaf(c2, x2.x, c3 * x3.x));
    v.y = fmaf(c1, x1.y, fmaf(c2, x2.y, c3 * x3.y));
    v.z = fmaf(c1, x1.z, fmaf(c2, x2.z, c3 * x3.z));
    v.w = fmaf(c1, x1.w, fmaf(c2, x2.w, c3 * x3.w));
    if (r == c + 0) v.x += c0;
    if (r == c + 1) v.y += c0;
    if (r == c + 2) v.z += c0;
    if (r == c + 3) v.w += c0;
    if (addsrc) {
      const float4 a = *(const float4*)(addsrc + e);
      v.x += a.x; v.y += a.y; v.z += a.z; v.w += a.w;
    }
    *(float4*)(dst + e) = v;
  }
  __syncthreads();
}

__global__ __launch_bounds__(NT) void s4_setup(const float* __restrict__ u,
    const float* __restrict__ A, const float* __restrict__ Bv,
    const float* __restrict__ Cv, const float* __restrict__ logdt,
    float* __restrict__ ws) {
  if (blockIdx.x > 0) {
    const int idx = (blockIdx.x - 1) * NT + threadIdx.x;  // 0..16383
    ws[4096 + idx] = u[(size_t)idx * 1024];
    return;
  }
  __shared__ __align__(16) float S0[MB];
  __shared__ __align__(16) unsigned short FRAG[16384];
  __shared__ float vB[64], v1[64], v2[64], v3[64], va[64], vb[64], vg[64];
  __shared__ int s_s;
  float* vscr = (float*)FRAG;  // overlay: only used by the 1-norm (pre-mm)

  const int t = threadIdx.x;
  float* kbuf = ws;
  float* gX   = ws + 20480;
  float* gX2  = ws + 24832;
  float* gX3  = ws + 29184;
  float* gU0  = ws + 33536;
  float* gU1  = ws + 37888;
  float* gBRT = ws + 42240;
  float* gCQT = ws + 46592;
  const float dt = expf(logdt[0]);

  const float invf[17] = {1.f, 1.f, 1.f / 2.f, 1.f / 6.f, 1.f / 24.f, 1.f / 120.f,
                          1.f / 720.f, 1.f / 5040.f, 1.f / 40320.f, 1.f / 362880.f,
                          1.f / 3628800.f, 1.f / 39916800.f, 1.f / 479001600.f,
                          1.f / 6.2270208e9f, 1.f / 8.71782912e10f,
                          1.f / 1.307674368e12f, 1.f / 2.0922789888e13f};

  // ---- 1-norm of dt*A -> s (theta = 2) ----
  {
    const int j = t & 63, w = t >> 6;
    float p = 0.f;
#pragma unroll
    for (int ii = 0; ii < 16; ++ii) p += fabsf(A[(w * 16 + ii) * 64 + j]);
    vscr[t] = p;
    __syncthreads();
    if (t < 64) {
      float cs = vscr[t] + vscr[64 + t] + vscr[128 + t] + vscr[192 + t];
      cs *= dt;
#pragma unroll
      for (int off = 32; off > 0; off >>= 1) cs = fmaxf(cs, __shfl_xor(cs, off));
      if (t == 0) {
        int s = 0;
        while (cs > 2.0f && s < 30) { cs *= 0.5f; ++s; }
        s_s = s;
      }
    }
    __syncthreads();
  }
  const int sq = s_s;
  const float scl = ldexpf(dt, -sq);

  // ---- X -> S0 and gX; vB ----
  {
    const int r = t >> 2, cb = (t & 3) * 16;
#pragma unroll
    for (int j = 0; j < 16; j += 4) {
      const float4 a4 = *(const float4*)(A + r * 64 + cb + j);
      float4 x;
      x.x = a4.x * scl; x.y = a4.y * scl; x.z = a4.z * scl; x.w = a4.w * scl;
      *(float4*)(S0 + r * MP + cb + j) = x;
      *(float4*)(gX + r * MP + cb + j) = x;
    }
    if (t < 64) vB[t] = Bv[t];
    __syncthreads();
  }

  // ---- powers: X2 (S0, +gX2), X3 (gX3), X4 (S0 in-place) ----
  mm(S0, S0, 0, S0, MP, gX2, 4, 4, 0, 0, FRAG);        // X2
  mm(gX, S0, 0, gX3, MP, nullptr, 4, 4, 0, 0, FRAG);   // X3 = X*X2
  mm(S0, S0, 0, S0, MP, nullptr, 4, 4, 0, 0, FRAG);    // X4 = X2*X2

  // ---- phi1(X)*B via PS on vectors (deg-15, groups of 4 in X4) ----
  mv64row(gX,  vB, v1, nullptr, 0);
  mv64row(gX2, vB, v2, nullptr, 0);
  mv64row(gX3, vB, v3, nullptr, 0);
  if (t < 64)
    va[t] = invf[13] * vB[t] + invf[14] * v1[t] + invf[15] * v2[t] + invf[16] * v3[t];
  __syncthreads();
  mv64row(S0, va, vb, nullptr, 0);
  if (t < 64)
    va[t] = invf[9] * vB[t] + invf[10] * v1[t] + invf[11] * v2[t] + invf[12] * v3[t] + vb[t];
  __syncthreads();
  mv64row(S0, va, vb, nullptr, 0);
  if (t < 64)
    va[t] = invf[5] * vB[t] + invf[6] * v1[t] + invf[7] * v2[t] + invf[8] * v3[t] + vb[t];
  __syncthreads();
  mv64row(S0, va, vb, nullptr, 0);
  if (t < 64)
    vg[t] = invf[1] * vB[t] + invf[2] * v1[t] + invf[3] * v2[t] + invf[4] * v3[t] + vb[t];
  __syncthreads();

  // ---- e^X: Taylor-15 PS Horner (B-operand X4 in S0) ----
  buildG(gU0, gX, gX2, gX3, invf[12], invf[13], invf[14], invf[15], nullptr);
  mm(gU0, S0, 0, gU1, MP, nullptr, 4, 4, 0, 0, FRAG);
  buildG(gU1, gX, gX2, gX3, invf[8], invf[9], invf[10], invf[11], gU1);
  mm(gU1, S0, 0, gU0, MP, nullptr, 4, 4, 0, 0, FRAG);
  buildG(gU0, gX, gX2, gX3, invf[4], invf[5], invf[6], invf[7], gU0);
  mm(gU0, S0, 0, S0, MP, nullptr, 4, 4, 0, 0, FRAG);   // -> S0 (over X4)
  buildG(S0, gX, gX2, gX3, invf[0], invf[1], invf[2], invf[3], S0);  // S0 = e^X

  // ---- squarings + phi1 doubling: g <- (F+I)g/2 (ping-pong vg/va) ----
  float* vcur = vg;
  float* vnxt = va;
  for (int it = 0; it < sq; ++it) {
    mv64row(S0, vcur, vnxt, nullptr, 1);  // vnxt = 0.5*(S0*vcur + vcur)
    { float* tmp = vcur; vcur = vnxt; vnxt = tmp; }
    mm(S0, S0, 0, S0, MP, nullptr, 4, 4, 0, 0, FRAG);
  }
  // S0 = Abar, vcur = phi1 vector

  // ---- BRT rows 0..15: bbar then Abar^r bbar (row store folded into mv) ----
  if (t < 64) {
    const float bb = dt * vcur[t];
    v1[t] = bb;
    gBRT[t] = bb;
  }
  __syncthreads();
  {
    float* vc = v1; float* vn = v2;
    for (int r = 1; r < 16; ++r) {
      mv64row(S0, vc, vn, gBRT + r * MP, 0);
      float* tmp = vc; vc = vn; vn = tmp;
    }
  }

  // ---- P-chain (in-place) + BRT widenings ----
  mm(S0, S0, 0, S0, MP, nullptr, 4, 4, 0, 0, FRAG);        // P2
  mm(S0, S0, 0, S0, MP, nullptr, 4, 4, 0, 0, FRAG);        // P4
  mm(S0, S0, 0, S0, MP, nullptr, 4, 4, 0, 0, FRAG);        // P8
  mm(S0, S0, 0, S0, MP, nullptr, 4, 4, 0, 0, FRAG);        // P16
  mm(gBRT, S0, 1, gBRT, MP, nullptr, 1, 4, 16, 0, FRAG);   // rows16:32 = BRT0:16*P16^T
  mm(S0, S0, 0, S0, MP, nullptr, 4, 4, 0, 0, FRAG);        // P32
  mm(gBRT, S0, 1, gBRT, MP, nullptr, 2, 4, 32, 0, FRAG);   // rows32:64
  mm(S0, S0, 0, S0, MP, nullptr, 4, 4, 0, 0, FRAG);        // P64

  // ---- CQT rows 0..15: c then (P64^T)^q c (row store folded into mv) ----
  if (t < 64) {
    const float cc = Cv[t];
    v1[t] = cc;
    gCQT[t] = cc;
  }
  __syncthreads();
  {
    float* vc = v1; float* vn = v2;
    for (int qx = 1; qx < 16; ++qx) {
      mv64colT(S0, vc, vn, gCQT + qx * MP);
      float* tmp = vc; vc = vn; vn = tmp;
    }
  }

  // ---- A-chain (in-place) + CQT widenings ----
  mm(S0, S0, 0, S0, MP, nullptr, 4, 4, 0, 0, FRAG);        // A128
  mm(S0, S0, 0, S0, MP, nullptr, 4, 4, 0, 0, FRAG);        // A256
  mm(S0, S0, 0, S0, MP, nullptr, 4, 4, 0, 0, FRAG);        // A512
  mm(S0, S0, 0, S0, MP, nullptr, 4, 4, 0, 0, FRAG);        // A1024
  mm(gCQT, S0, 0, gCQT, MP, nullptr, 1, 4, 16, 0, FRAG);   // rows16:32 = CQT0:16*A1024
  mm(S0, S0, 0, S0, MP, nullptr, 4, 4, 0, 0, FRAG);        // A2048
  mm(gCQT, S0, 0, gCQT, MP, nullptr, 2, 4, 32, 0, FRAG);   // rows32:64

  // ---- k[q*64+r] = sum_i CQT[q][i]*BRT[r][i] ----
  mm(gCQT, gBRT, 1, kbuf, 64, nullptr, 4, 4, 0, 0, FRAG);
}

// Fused conv + broadcast. 4096 blocks x 256 threads; block computes y[t0..t0+3]
// for one batch, then streams 4 rows x 1024 cols of broadcast stores.
// Conv: thread owns source chunks s0 = 4*tid + 1024*iter (16B-aligned since t0
// and s0 are multiples of 4). y[t0+d] += sum_i k[b0+d-i]*u[s0+i], b0=t0-s0;
// k indices d-i in [-3,3] served by two aligned float4 (k0=k[b0..b0+3],
// k1=k[b0-4..b0-1], zeroed at b0==0 which exactly masks the invalid terms).
__global__ __launch_bounds__(256) void s4_out(const float* __restrict__ ws,
                                              const float* __restrict__ Dp,
                                              float* __restrict__ out) {
  const int bid = blockIdx.x;
  const int b = bid >> 10;
  const int t0 = (bid & 1023) << 2;
  const float* kb = ws;
  const float* ub = ws + 4096 + (b << 12);
  const int tid = threadIdx.x;

  float a0 = 0.f, a1 = 0.f, a2 = 0.f, a3 = 0.f;
  for (int s0 = tid << 2; s0 <= t0; s0 += 1024) {
    const float4 uv = *(const float4*)(ub + s0);
    const int b0 = t0 - s0;  // multiple of 4, >= 0
    const float4 k0 = *(const float4*)(kb + b0);
    float4 k1 = make_float4(0.f, 0.f, 0.f, 0.f);
    if (b0 >= 4) k1 = *(const float4*)(kb + b0 - 4);
    // d=0: e=-i -> k0.x, k1.w, k1.z, k1.y
    a0 = fmaf(k0.x, uv.x, a0);
    a0 = fmaf(k1.w, uv.y, a0);
    a0 = fmaf(k1.z, uv.z, a0);
    a0 = fmaf(k1.y, uv.w, a0);
    // d=1: k0.y, k0.x, k1.w, k1.z
    a1 = fmaf(k0.y, uv.x, a1);
    a1 = fmaf(k0.x, uv.y, a1);
    a1 = fmaf(k1.w, uv.z, a1);
    a1 = fmaf(k1.z, uv.w, a1);
    // d=2: k0.z, k0.y, k0.x, k1.w
    a2 = fmaf(k0.z, uv.x, a2);
    a2 = fmaf(k0.y, uv.y, a2);
    a2 = fmaf(k0.x, uv.z, a2);
    a2 = fmaf(k1.w, uv.w, a2);
    // d=3: k0.w, k0.z, k0.y, k0.x
    a3 = fmaf(k0.w, uv.x, a3);
    a3 = fmaf(k0.z, uv.y, a3);
    a3 = fmaf(k0.y, uv.z, a3);
    a3 = fmaf(k0.x, uv.w, a3);
  }
#pragma unroll
  for (int off = 32; off > 0; off >>= 1) {
    a0 += __shfl_xor(a0, off);
    a1 += __shfl_xor(a1, off);
    a2 += __shfl_xor(a2, off);
    a3 += __shfl_xor(a3, off);
  }
  __shared__ float red[4][4];
  __shared__ float sy[4];
  if ((tid & 63) == 0) {
    const int w = tid >> 6;
    red[0][w] = a0; red[1][w] = a1; red[2][w] = a2; red[3][w] = a3;
  }
  __syncthreads();
  if (tid < 4)
    sy[tid] = red[tid][0] + red[tid][1] + red[tid][2] + red[tid][3] +
              Dp[0] * ub[t0 + tid];
  __syncthreads();
  const int row = tid >> 6, l = tid & 63;
  const float y = sy[row];
  const v4f y4 = {y, y, y, y};
  v4f* dst = (v4f*)(out + ((size_t)(b << 12) + t0 + row) * 1024);
  __builtin_nontemporal_store(y4, dst + l);
  __builtin_nontemporal_store(y4, dst + l + 64);
  __builtin_nontemporal_store(y4, dst + l + 128);
  __builtin_nontemporal_store(y4, dst + l + 192);
}

extern "C" void kernel_launch(void* const* d_in, const int* in_sizes, int n_in,
                              void* d_out, int out_size, void* d_ws, size_t ws_size,
                              hipStream_t stream) {
  const float* u  = (const float*)d_in[0];
  const float* A  = (const float*)d_in[1];
  const float* B  = (const float*)d_in[2];
  const float* C  = (const float*)d_in[3];
  const float* D  = (const float*)d_in[4];
  const float* ld = (const float*)d_in[5];
  float* ws = (float*)d_ws;  // needs >= 203776 bytes

  s4_setup<<<65, NT, 0, stream>>>(u, A, B, C, ld, ws);
  s4_out<<<4096, 256, 0, stream>>>(ws, D, (float*)d_out);
}